// Round 7
// baseline (1039.352 us; speedup 1.0000x reference)
//
#include <hip/hip_runtime.h>

// Problem constants (from reference)
#define MM   6
#define BB   128
#define TT   32
#define DIN  64
#define HH   512
#define EE   512
#define NEMB 32
#define XP   72    // padded x row (bf16 elems): 144 B stride
#define HP   520   // padded h row (bf16 elems): 1040 B stride
#define ROWS 64    // token rows per block = 2 batches
#define MAXCH 64   // max chunks per id = ceil(128/2)

typedef __attribute__((ext_vector_type(8))) short bf16x8;   // MFMA A/B frag (4 VGPR)
typedef __attribute__((ext_vector_type(4))) float f32x4;    // MFMA C/D frag

static __device__ __forceinline__ unsigned short f2bf(float f) {
    unsigned int u = __float_as_uint(f);
    u += 0x7FFFu + ((u >> 16) & 1u);
    return (unsigned short)(u >> 16);
}
static __device__ __forceinline__ float bf2f(unsigned short h) {
    return __uint_as_float(((unsigned int)h) << 16);
}

// ---- kernel 1: bucket batches by embodiment id (1 block, 128 threads) ----
__global__ void bucket_k(const int* __restrict__ emb_ids,
                         int* __restrict__ cnt, int* __restrict__ lists) {
    int t = threadIdx.x;
    if (t < NEMB) cnt[t] = 0;
    __syncthreads();
    if (t < BB) {
        int id = emb_ids[t];
        int slot = atomicAdd(&cnt[id], 1);
        lists[id * BB + slot] = t;
    }
}

// ---- kernel 2: grouped 2-layer MLP, 64 rows (2 batches) x 512 cols per block ----
// Fragment layouts (HW-verified, learn_hip m89/m92):
//   A (16x32): lane l, elem i -> A[l&15][(l>>4)*8 + i]
//   B (32x16): lane l, elem i -> B[(l>>4)*8 + i][l&15]
//   D (16x16): lane l, reg  r -> D[(l>>4)*4 + r][l&15]
// 3-term split: x*w ~= xh*wh + xh*wl + xl*wh
__global__ __launch_bounds__(512, 2) void tok_mfma2(
    const float* __restrict__ state,   // (B, T, M*DIN)
    const int*   __restrict__ cnt,     // (NEMB)
    const int*   __restrict__ lists,   // (NEMB, BB)
    const float* __restrict__ W1,      // (M, NEMB, DIN, H)
    const float* __restrict__ b1,      // (M, NEMB, H)
    const float* __restrict__ W2,      // (M, NEMB, H, E)
    const float* __restrict__ b2,      // (M, NEMB, E)
    const float* __restrict__ te,      // (M, E)
    float* __restrict__ out)           // (B, M*T, E)
{
    __shared__ __align__(16) unsigned short x_hi[ROWS][XP];
    __shared__ __align__(16) unsigned short x_lo[ROWS][XP];
    __shared__ __align__(16) unsigned short h_hi[ROWS][HP];
    __shared__ __align__(16) unsigned short h_lo[ROWS][HP];

    const int c  = blockIdx.x;         // chunk within id's batch list
    const int id = blockIdx.y;
    const int m  = blockIdx.z;
    const int n_b = cnt[id];
    if (c * 2 >= n_b) return;          // empty chunk
    const int nb  = (n_b - c * 2 >= 2) ? 2 : 1;
    const int ba0 = lists[id * BB + c * 2];
    const int ba1 = lists[id * BB + c * 2 + (nb - 1)];  // dup of ba0 when nb==1

    const int tid  = threadIdx.x;
    const int lane = tid & 63;
    const int w    = tid >> 6;         // wave 0..7: owns cols [w*64, w*64+64)
    const int lr   = lane & 15;
    const int lg   = lane >> 4;

    const float* W1p = W1 + (size_t)(m * NEMB + id) * DIN * HH;
    const float* b1p = b1 + (size_t)(m * NEMB + id) * HH;
    const float* W2p = W2 + (size_t)(m * NEMB + id) * HH * EE;
    const float* b2p = b2 + (size_t)(m * NEMB + id) * EE;
    const float* tep = te + m * EE;

    // ---- stage x (64 rows x 64 fp32) as bf16 hi/lo: 1024 float4, 2/thread ----
    #pragma unroll
    for (int kq = 0; kq < 2; ++kq) {
        int f  = kq * 512 + tid;       // 0..1023
        int r  = f >> 4;               // row 0..63
        int i4 = f & 15;
        int bsel = (r < 32) ? ba0 : ba1;
        const float* xg = state + ((size_t)bsel * TT + (r & 31)) * (MM * DIN) + m * DIN + i4 * 4;
        float4 v = *reinterpret_cast<const float4*>(xg);
        ushort4 hi, lo;
        hi.x = f2bf(v.x); lo.x = f2bf(v.x - bf2f(hi.x));
        hi.y = f2bf(v.y); lo.y = f2bf(v.y - bf2f(hi.y));
        hi.z = f2bf(v.z); lo.z = f2bf(v.z - bf2f(hi.z));
        hi.w = f2bf(v.w); lo.w = f2bf(v.w - bf2f(hi.w));
        *reinterpret_cast<ushort4*>(&x_hi[r][i4 * 4]) = hi;
        *reinterpret_cast<ushort4*>(&x_lo[r][i4 * 4]) = lo;
    }
    __syncthreads();

    // ---- layer 1: h = relu(x @ W1 + b1); wave w -> cols [w*64, w*64+64) ----
    bf16x8 xa_h[4][2], xa_l[4][2];     // [row-tile][k-step]
    #pragma unroll
    for (int rt = 0; rt < 4; ++rt)
        #pragma unroll
        for (int kk = 0; kk < 2; ++kk) {
            xa_h[rt][kk] = *reinterpret_cast<const bf16x8*>(&x_hi[rt * 16 + lr][kk * 32 + lg * 8]);
            xa_l[rt][kk] = *reinterpret_cast<const bf16x8*>(&x_lo[rt * 16 + lr][kk * 32 + lg * 8]);
        }

    #pragma unroll
    for (int j = 0; j < 4; ++j) {
        const int n = w * 64 + j * 16 + lr;
        float bv = b1p[n];
        f32x4 a[4];
        #pragma unroll
        for (int rt = 0; rt < 4; ++rt) { f32x4 t0 = {bv, bv, bv, bv}; a[rt] = t0; }
        #pragma unroll
        for (int kk = 0; kk < 2; ++kk) {
            const float* wp = W1p + (size_t)(kk * 32 + lg * 8) * HH + n;
            bf16x8 bh, bl;
            #pragma unroll
            for (int i = 0; i < 8; ++i) {
                float wv = wp[(size_t)i * HH];
                unsigned short h_ = f2bf(wv);
                bh[i] = (short)h_;
                bl[i] = (short)f2bf(wv - bf2f(h_));
            }
            #pragma unroll
            for (int rt = 0; rt < 4; ++rt) {
                a[rt] = __builtin_amdgcn_mfma_f32_16x16x32_bf16(xa_h[rt][kk], bh, a[rt], 0, 0, 0);
                a[rt] = __builtin_amdgcn_mfma_f32_16x16x32_bf16(xa_h[rt][kk], bl, a[rt], 0, 0, 0);
                a[rt] = __builtin_amdgcn_mfma_f32_16x16x32_bf16(xa_l[rt][kk], bh, a[rt], 0, 0, 0);
            }
        }
        // relu + hi/lo split -> h LDS (D row = rt*16 + lg*4 + r, col n)
        #pragma unroll
        for (int rt = 0; rt < 4; ++rt)
            #pragma unroll
            for (int r = 0; r < 4; ++r) {
                float hv = fmaxf(a[rt][r], 0.0f);
                unsigned short hh = f2bf(hv);
                h_hi[rt * 16 + lg * 4 + r][n] = hh;
                h_lo[rt * 16 + lg * 4 + r][n] = f2bf(hv - bf2f(hh));
            }
    }
    __syncthreads();

    // ---- layer 2: z = h @ W2 + b2 + te ----
    float bias2[4];
    #pragma unroll
    for (int j = 0; j < 4; ++j) {
        int n = w * 64 + j * 16 + lr;
        bias2[j] = b2p[n] + tep[n];
    }
    f32x4 acc[4][4];                    // [row-tile][j]
    #pragma unroll
    for (int rt = 0; rt < 4; ++rt)
        #pragma unroll
        for (int j = 0; j < 4; ++j) {
            f32x4 t0 = {bias2[j], bias2[j], bias2[j], bias2[j]};
            acc[rt][j] = t0;
        }

    for (int kk = 0; kk < 16; ++kk) {
        bf16x8 ah[4], al[4];
        #pragma unroll
        for (int rt = 0; rt < 4; ++rt) {
            ah[rt] = *reinterpret_cast<const bf16x8*>(&h_hi[rt * 16 + lr][kk * 32 + lg * 8]);
            al[rt] = *reinterpret_cast<const bf16x8*>(&h_lo[rt * 16 + lr][kk * 32 + lg * 8]);
        }
        #pragma unroll
        for (int j = 0; j < 4; ++j) {
            const float* wp = W2p + (size_t)(kk * 32 + lg * 8) * EE + (w * 64 + j * 16 + lr);
            bf16x8 bh, bl;
            #pragma unroll
            for (int i = 0; i < 8; ++i) {
                float wv = wp[(size_t)i * EE];
                unsigned short h_ = f2bf(wv);
                bh[i] = (short)h_;
                bl[i] = (short)f2bf(wv - bf2f(h_));
            }
            #pragma unroll
            for (int rt = 0; rt < 4; ++rt) {
                acc[rt][j] = __builtin_amdgcn_mfma_f32_16x16x32_bf16(ah[rt], bh, acc[rt][j], 0, 0, 0);
                acc[rt][j] = __builtin_amdgcn_mfma_f32_16x16x32_bf16(ah[rt], bl, acc[rt][j], 0, 0, 0);
                acc[rt][j] = __builtin_amdgcn_mfma_f32_16x16x32_bf16(al[rt], bh, acc[rt][j], 0, 0, 0);
            }
        }
    }

    // ---- epilogue: out[batch, m*T + (rt&1)*16 + lg*4 + r, n] ----
    #pragma unroll
    for (int rt = 0; rt < 4; ++rt) {
        int bi = rt >> 1;              // which batch half (local rows 16rt..16rt+15)
        if (bi >= nb) continue;        // nb==1: skip duplicated half
        int bglob = (bi == 0) ? ba0 : ba1;
        float* outp = out + (((size_t)bglob * MM + m) * TT + (rt & 1) * 16 + lg * 4) * EE;
        #pragma unroll
        for (int j = 0; j < 4; ++j) {
            int n = w * 64 + j * 16 + lr;
            #pragma unroll
            for (int r = 0; r < 4; ++r)
                outp[(size_t)r * EE + n] = acc[rt][j][r];
        }
    }
}

extern "C" void kernel_launch(void* const* d_in, const int* in_sizes, int n_in,
                              void* d_out, int out_size, void* d_ws, size_t ws_size,
                              hipStream_t stream) {
    const float* state   = (const float*)d_in[0];
    const int*   emb_ids = (const int*)d_in[1];
    const float* W1      = (const float*)d_in[2];
    const float* b1      = (const float*)d_in[3];
    const float* W2      = (const float*)d_in[4];
    const float* b2      = (const float*)d_in[5];
    const float* te      = (const float*)d_in[6];
    float*       out     = (float*)d_out;

    int* cnt   = (int*)d_ws;                // 32 ints
    int* lists = cnt + NEMB;                // 32*128 ints

    bucket_k<<<dim3(1), dim3(128), 0, stream>>>(emb_ids, cnt, lists);
    tok_mfma2<<<dim3(MAXCH, NEMB, MM), dim3(512), 0, stream>>>(
        state, cnt, lists, W1, b1, W2, b2, te, out);
}

// Round 9
// 415.590 us; speedup vs baseline: 2.5009x; 2.5009x over previous
//
#include <hip/hip_runtime.h>

// Problem constants (from reference)
#define MM   6
#define BB   128
#define TT   32
#define DIN  64
#define HH   512
#define EE   512
#define NEMB 32
#define XP   72    // padded x row (bf16): 144 B stride
#define HP   520   // padded h row (bf16): 1040 B stride
#define TRS  36    // transposed-bounce row stride (dwords): 144 B, 16B-aligned, 2-way banks

typedef __attribute__((ext_vector_type(8))) short bf16x8;   // MFMA A/B frag
typedef __attribute__((ext_vector_type(4))) float f32x4;    // MFMA C/D frag

static __device__ __forceinline__ unsigned short f2bf(float f) {
    unsigned int u = __float_as_uint(f);
    u += 0x7FFFu + ((u >> 16) & 1u);
    return (unsigned short)(u >> 16);
}
static __device__ __forceinline__ float bf2f(unsigned short h) {
    return __uint_as_float(((unsigned int)h) << 16);
}

// ---- kernel 1: build id-major/m-secondary work order (1 block, 128 thr) ----
__global__ void order_k(const int* __restrict__ emb_ids, int* __restrict__ ent) {
    __shared__ int cnt_s[NEMB], psum_s[NEMB], slot_s[BB], id_s[BB];
    int t = threadIdx.x;
    if (t < NEMB) cnt_s[t] = 0;
    __syncthreads();
    if (t < BB) { int id = emb_ids[t]; id_s[t] = id; slot_s[t] = atomicAdd(&cnt_s[id], 1); }
    __syncthreads();
    if (t == 0) { int r = 0; for (int i = 0; i < NEMB; ++i) { psum_s[i] = r; r += cnt_s[i]; } }
    __syncthreads();
    if (t < BB) {
        int id = id_s[t], sl = slot_s[t], base = psum_s[id] * MM, c = cnt_s[id];
        for (int mm = 0; mm < MM; ++mm) ent[base + mm * c + sl] = (t << 3) | mm;
    }
}

// ---- kernel 2: per-(b,m) MLP block; vectorized W2 via transposed LDS bounce ----
// Fragment layouts (HW-verified, learn_hip m89/m92):
//   A (16x32): lane l, elem i -> A[l&15][(l>>4)*8 + i]
//   B (32x16): lane l, elem i -> B[(l>>4)*8 + i][l&15]
//   D (16x16): lane l, reg  r -> D[(l>>4)*4 + r][l&15]
// 3-term split: x*w ~= xh*wh + xh*wl + xl*wh
__global__ __launch_bounds__(256, 2) void tok_mfma4(
    const float* __restrict__ state,   // (B, T, M*DIN)
    const int*   __restrict__ ent,     // (768) sorted work items
    const float* __restrict__ W1,      // (M, NEMB, DIN, H)
    const float* __restrict__ b1,      // (M, NEMB, H)
    const float* __restrict__ W2,      // (M, NEMB, H, E)
    const float* __restrict__ b2,      // (M, NEMB, E)
    const float* __restrict__ te,      // (M, E)
    const int*   __restrict__ emb_ids, // (B)
    float* __restrict__ out)           // (B, M*T, E)
{
    // region A: x hi/lo during layer1 (9216 B); W2 transposed bounce during layer2
    // (4 waves x 16 cols x 36 dwords x 4 B = 9216 B)
    __shared__ __align__(16) unsigned char regA[10240];
    __shared__ __align__(16) unsigned short h_hi[TT][HP];
    __shared__ __align__(16) unsigned short h_lo[TT][HP];

    const int bid = blockIdx.x;
    const int s   = (bid & 7) * 96 + (bid >> 3);   // XCD-chunked sorted index
    const int e   = ent[s];
    const int b   = e >> 3;
    const int m   = e & 7;
    const int id  = emb_ids[b];

    const int tid  = threadIdx.x;
    const int lane = tid & 63;
    const int w    = tid >> 6;         // wave 0..3: owns cols [w*128, w*128+128)
    const int lr   = lane & 15;
    const int lg   = lane >> 4;

    const float* W1p = W1 + (size_t)(m * NEMB + id) * DIN * HH;
    const float* b1p = b1 + (size_t)(m * NEMB + id) * HH;
    const float* W2p = W2 + (size_t)(m * NEMB + id) * HH * EE;
    const float* b2p = b2 + (size_t)(m * NEMB + id) * EE;
    const float* tep = te + m * EE;
    const float* xg  = state + (size_t)b * TT * (MM * DIN) + m * DIN;

    unsigned short (*x_hi)[XP] = (unsigned short(*)[XP])regA;
    unsigned short (*x_lo)[XP] = (unsigned short(*)[XP])(regA + 4608);

    // ---- stage x (32x64 fp32) as bf16 hi/lo ----
    #pragma unroll
    for (int kq = 0; kq < 2; ++kq) {
        int f  = kq * 256 + tid;       // 0..511 float4 slots
        int t  = f >> 4;
        int i4 = f & 15;
        float4 v = *reinterpret_cast<const float4*>(xg + (size_t)t * (MM * DIN) + i4 * 4);
        ushort4 hi, lo;
        hi.x = f2bf(v.x); lo.x = f2bf(v.x - bf2f(hi.x));
        hi.y = f2bf(v.y); lo.y = f2bf(v.y - bf2f(hi.y));
        hi.z = f2bf(v.z); lo.z = f2bf(v.z - bf2f(hi.z));
        hi.w = f2bf(v.w); lo.w = f2bf(v.w - bf2f(hi.w));
        *reinterpret_cast<ushort4*>(&x_hi[t][i4 * 4]) = hi;
        *reinterpret_cast<ushort4*>(&x_lo[t][i4 * 4]) = lo;
    }
    __syncthreads();

    // ---- layer 1: h = relu(x @ W1 + b1); wave w -> cols [w*128, w*128+128) ----
    bf16x8 xa_h[2][2], xa_l[2][2];     // [row-tile][k-step]
    #pragma unroll
    for (int rt = 0; rt < 2; ++rt)
        #pragma unroll
        for (int kk = 0; kk < 2; ++kk) {
            xa_h[rt][kk] = *reinterpret_cast<const bf16x8*>(&x_hi[rt * 16 + lr][kk * 32 + lg * 8]);
            xa_l[rt][kk] = *reinterpret_cast<const bf16x8*>(&x_lo[rt * 16 + lr][kk * 32 + lg * 8]);
        }

    #pragma unroll
    for (int j = 0; j < 8; ++j) {
        const int n = w * 128 + j * 16 + lr;
        float bv = b1p[n];
        f32x4 a0 = {bv, bv, bv, bv};
        f32x4 a1 = {bv, bv, bv, bv};
        #pragma unroll
        for (int kk = 0; kk < 2; ++kk) {
            const float* wp = W1p + (size_t)(kk * 32 + lg * 8) * HH + n;
            bf16x8 bh, bl;
            #pragma unroll
            for (int i = 0; i < 8; ++i) {
                float wv = wp[(size_t)i * HH];
                unsigned short h_ = f2bf(wv);
                bh[i] = (short)h_;
                bl[i] = (short)f2bf(wv - bf2f(h_));
            }
            a0 = __builtin_amdgcn_mfma_f32_16x16x32_bf16(xa_h[0][kk], bh, a0, 0, 0, 0);
            a0 = __builtin_amdgcn_mfma_f32_16x16x32_bf16(xa_h[0][kk], bl, a0, 0, 0, 0);
            a0 = __builtin_amdgcn_mfma_f32_16x16x32_bf16(xa_l[0][kk], bh, a0, 0, 0, 0);
            a1 = __builtin_amdgcn_mfma_f32_16x16x32_bf16(xa_h[1][kk], bh, a1, 0, 0, 0);
            a1 = __builtin_amdgcn_mfma_f32_16x16x32_bf16(xa_h[1][kk], bl, a1, 0, 0, 0);
            a1 = __builtin_amdgcn_mfma_f32_16x16x32_bf16(xa_l[1][kk], bh, a1, 0, 0, 0);
        }
        #pragma unroll
        for (int r = 0; r < 4; ++r) {
            float h0 = fmaxf(a0[r], 0.0f);
            unsigned short hh0 = f2bf(h0);
            h_hi[lg * 4 + r][n] = hh0;
            h_lo[lg * 4 + r][n] = f2bf(h0 - bf2f(hh0));
            float h1 = fmaxf(a1[r], 0.0f);
            unsigned short hh1 = f2bf(h1);
            h_hi[16 + lg * 4 + r][n] = hh1;
            h_lo[16 + lg * 4 + r][n] = f2bf(h1 - bf2f(hh1));
        }
    }
    __syncthreads();   // h published; x region dead -> reuse as transposed bounce

    // ---- layer 2: z = h @ W2 + b2 + te ----
    float* bounce = (float*)(regA + w * 2304);   // [16 cols][TRS dwords]
    const int wr = lane >> 2;                    // load row within 16
    const int wc = (lane & 3) * 4;               // load col base

    float bias2[8];
    #pragma unroll
    for (int j = 0; j < 8; ++j) {
        int n = w * 128 + j * 16 + lr;
        bias2[j] = b2p[n] + tep[n];
    }
    f32x4 acc[2][8];
    #pragma unroll
    for (int rt = 0; rt < 2; ++rt)
        #pragma unroll
        for (int j = 0; j < 8; ++j) {
            f32x4 t0 = {bias2[j], bias2[j], bias2[j], bias2[j]};
            acc[rt][j] = t0;
        }

    // preload frag (kk=0, j=0): rows wr and 16+wr, cols w*128 + wc..wc+3
    const float* src0 = W2p + (size_t)wr * EE + (w * 128 + wc);
    float4 ra = *reinterpret_cast<const float4*>(src0);
    float4 rb = *reinterpret_cast<const float4*>(src0 + (size_t)16 * EE);

    for (int kk = 0; kk < 16; ++kk) {
        // A-frags (h) for both row-tiles, hi and lo
        bf16x8 ah0 = *reinterpret_cast<const bf16x8*>(&h_hi[lr][kk * 32 + lg * 8]);
        bf16x8 al0 = *reinterpret_cast<const bf16x8*>(&h_lo[lr][kk * 32 + lg * 8]);
        bf16x8 ah1 = *reinterpret_cast<const bf16x8*>(&h_hi[16 + lr][kk * 32 + lg * 8]);
        bf16x8 al1 = *reinterpret_cast<const bf16x8*>(&h_lo[16 + lr][kk * 32 + lg * 8]);
        #pragma unroll
        for (int j = 0; j < 8; ++j) {
            // order: previous frag's bounce reads must precede these writes
            asm volatile("" ::: "memory");
            // publish current frag TRANSPOSED: bounce[col][row]
            bounce[(wc + 0) * TRS + wr] = ra.x;
            bounce[(wc + 1) * TRS + wr] = ra.y;
            bounce[(wc + 2) * TRS + wr] = ra.z;
            bounce[(wc + 3) * TRS + wr] = ra.w;
            bounce[(wc + 0) * TRS + 16 + wr] = rb.x;
            bounce[(wc + 1) * TRS + 16 + wr] = rb.y;
            bounce[(wc + 2) * TRS + 16 + wr] = rb.z;
            bounce[(wc + 3) * TRS + 16 + wr] = rb.w;
            // issue next frag's global loads (overlap with compute below)
            int nkk = (j == 7) ? kk + 1 : kk;
            int nj  = (j == 7) ? 0 : j + 1;
            const float* nsrc = (nkk < 16)
                ? W2p + (size_t)(nkk * 32 + wr) * EE + (w * 128 + nj * 16 + wc)
                : src0;   // dummy in-bounds
            float4 na = *reinterpret_cast<const float4*>(nsrc);
            float4 nb = *reinterpret_cast<const float4*>(nsrc + (size_t)16 * EE);
            // wait bounce writes, then contiguous b128 reads + split
            asm volatile("s_waitcnt lgkmcnt(0)" ::: "memory");
            float4 f0 = *reinterpret_cast<const float4*>(&bounce[lr * TRS + lg * 8]);
            float4 f1 = *reinterpret_cast<const float4*>(&bounce[lr * TRS + lg * 8 + 4]);
            bf16x8 bh, bl;
            {
                const float* fv0 = &f0.x;
                const float* fv1 = &f1.x;
                #pragma unroll
                for (int i = 0; i < 4; ++i) {
                    unsigned short hb = f2bf(fv0[i]);
                    bh[i] = (short)hb;
                    bl[i] = (short)f2bf(fv0[i] - bf2f(hb));
                }
                #pragma unroll
                for (int i = 0; i < 4; ++i) {
                    unsigned short hb = f2bf(fv1[i]);
                    bh[4 + i] = (short)hb;
                    bl[4 + i] = (short)f2bf(fv1[i] - bf2f(hb));
                }
            }
            acc[0][j] = __builtin_amdgcn_mfma_f32_16x16x32_bf16(ah0, bh, acc[0][j], 0, 0, 0);
            acc[0][j] = __builtin_amdgcn_mfma_f32_16x16x32_bf16(ah0, bl, acc[0][j], 0, 0, 0);
            acc[0][j] = __builtin_amdgcn_mfma_f32_16x16x32_bf16(al0, bh, acc[0][j], 0, 0, 0);
            acc[1][j] = __builtin_amdgcn_mfma_f32_16x16x32_bf16(ah1, bh, acc[1][j], 0, 0, 0);
            acc[1][j] = __builtin_amdgcn_mfma_f32_16x16x32_bf16(ah1, bl, acc[1][j], 0, 0, 0);
            acc[1][j] = __builtin_amdgcn_mfma_f32_16x16x32_bf16(al1, bh, acc[1][j], 0, 0, 0);
            ra = na; rb = nb;
        }
    }

    // ---- epilogue: out[b, m*T + row, n] ----
    float* outp = out + ((size_t)(b * MM + m) * TT) * EE;
    #pragma unroll
    for (int rt = 0; rt < 2; ++rt)
        #pragma unroll
        for (int j = 0; j < 8; ++j) {
            int n = w * 128 + j * 16 + lr;
            #pragma unroll
            for (int r = 0; r < 4; ++r) {
                int row = rt * 16 + lg * 4 + r;
                outp[(size_t)row * EE + n] = acc[rt][j][r];
            }
        }
}

extern "C" void kernel_launch(void* const* d_in, const int* in_sizes, int n_in,
                              void* d_out, int out_size, void* d_ws, size_t ws_size,
                              hipStream_t stream) {
    const float* state   = (const float*)d_in[0];
    const int*   emb_ids = (const int*)d_in[1];
    const float* W1      = (const float*)d_in[2];
    const float* b1      = (const float*)d_in[3];
    const float* W2      = (const float*)d_in[4];
    const float* b2      = (const float*)d_in[5];
    const float* te      = (const float*)d_in[6];
    float*       out     = (float*)d_out;

    int* ent = (int*)d_ws;                    // 768 ints

    order_k<<<dim3(1), dim3(128), 0, stream>>>(emb_ids, ent);
    tok_mfma4<<<dim3(BB * MM), dim3(256), 0, stream>>>(
        state, ent, W1, b1, W2, b2, te, emb_ids, out);
}

// Round 10
// 387.004 us; speedup vs baseline: 2.6856x; 1.0739x over previous
//
#include <hip/hip_runtime.h>

// Problem constants (from reference)
#define MM   6
#define BB   128
#define TT   32
#define DIN  64
#define HH   512
#define EE   512
#define NEMB 32
#define XP   72    // padded x row (bf16): 144 B stride
#define HP   520   // padded h row (bf16): 1040 B stride

typedef __attribute__((ext_vector_type(8))) short bf16x8;   // MFMA A/B frag
typedef __attribute__((ext_vector_type(4))) float f32x4;    // MFMA C/D frag

static __device__ __forceinline__ unsigned short f2bf(float f) {   // RTNE
    unsigned int u = __float_as_uint(f);
    u += 0x7FFFu + ((u >> 16) & 1u);
    return (unsigned short)(u >> 16);
}
static __device__ __forceinline__ float bf2f(unsigned short h) {
    return __uint_as_float(((unsigned int)h) << 16);
}
static __device__ __forceinline__ unsigned short f2bf_t(float f) { // truncate (lo parts)
    return (unsigned short)(__float_as_uint(f) >> 16);
}

// ---- kernel 1: build id-major/m-secondary work order (1 block, 128 thr) ----
__global__ void order_k(const int* __restrict__ emb_ids, int* __restrict__ ent) {
    __shared__ int cnt_s[NEMB], psum_s[NEMB], slot_s[BB], id_s[BB];
    int t = threadIdx.x;
    if (t < NEMB) cnt_s[t] = 0;
    __syncthreads();
    if (t < BB) { int id = emb_ids[t]; id_s[t] = id; slot_s[t] = atomicAdd(&cnt_s[id], 1); }
    __syncthreads();
    if (t == 0) { int r = 0; for (int i = 0; i < NEMB; ++i) { psum_s[i] = r; r += cnt_s[i]; } }
    __syncthreads();
    if (t < BB) {
        int id = id_s[t], sl = slot_s[t], base = psum_s[id] * MM, c = cnt_s[id];
        for (int mm = 0; mm < MM; ++mm) ent[base + mm * c + sl] = (t << 3) | mm;
    }
}

// ---- kernel 2: per-(b,m) MLP; 8 waves x 64 out-cols; direct global B-frags ----
// Fragment layouts (HW-verified, learn_hip m89/m92):
//   A (16x32): lane l, elem i -> A[l&15][(l>>4)*8 + i]
//   B (32x16): lane l, elem i -> B[(l>>4)*8 + i][l&15]
//   D (16x16): lane l, reg  r -> D[(l>>4)*4 + r][l&15]
// 3-term split: x*w ~= xh*wh + xh*wl + xl*wh
__global__ __launch_bounds__(512, 4) void tok_mfma5(
    const float* __restrict__ state,   // (B, T, M*DIN)
    const int*   __restrict__ ent,     // (768) sorted work items
    const float* __restrict__ W1,      // (M, NEMB, DIN, H)
    const float* __restrict__ b1,      // (M, NEMB, H)
    const float* __restrict__ W2,      // (M, NEMB, H, E)
    const float* __restrict__ b2,      // (M, NEMB, E)
    const float* __restrict__ te,      // (M, E)
    const int*   __restrict__ emb_ids, // (B)
    float* __restrict__ out)           // (B, M*T, E)
{
    __shared__ __align__(16) unsigned short x_hi[TT][XP];
    __shared__ __align__(16) unsigned short x_lo[TT][XP];
    __shared__ __align__(16) unsigned short h_hi[TT][HP];
    __shared__ __align__(16) unsigned short h_lo[TT][HP];

    const int bid = blockIdx.x;
    const int s   = (bid & 7) * 96 + (bid >> 3);   // XCD-chunked sorted index
    const int e   = ent[s];
    const int b   = e >> 3;
    const int m   = e & 7;
    const int id  = emb_ids[b];

    const int tid  = threadIdx.x;
    const int lane = tid & 63;
    const int w    = tid >> 6;         // wave 0..7: owns cols [w*64, w*64+64)
    const int lr   = lane & 15;
    const int lg   = lane >> 4;

    const float* W1p = W1 + (size_t)(m * NEMB + id) * DIN * HH;
    const float* b1p = b1 + (size_t)(m * NEMB + id) * HH;
    const float* W2p = W2 + (size_t)(m * NEMB + id) * HH * EE;
    const float* b2p = b2 + (size_t)(m * NEMB + id) * EE;
    const float* tep = te + m * EE;
    const float* xg  = state + (size_t)b * TT * (MM * DIN) + m * DIN;

    // ---- stage x (32x64 fp32) as bf16 hi/lo: 512 float4 slots, 1/thread ----
    {
        int t  = tid >> 4;
        int i4 = tid & 15;
        float4 v = *reinterpret_cast<const float4*>(xg + (size_t)t * (MM * DIN) + i4 * 4);
        ushort4 hi, lo;
        hi.x = f2bf(v.x); lo.x = f2bf_t(v.x - bf2f(hi.x));
        hi.y = f2bf(v.y); lo.y = f2bf_t(v.y - bf2f(hi.y));
        hi.z = f2bf(v.z); lo.z = f2bf_t(v.z - bf2f(hi.z));
        hi.w = f2bf(v.w); lo.w = f2bf_t(v.w - bf2f(hi.w));
        *reinterpret_cast<ushort4*>(&x_hi[t][i4 * 4]) = hi;
        *reinterpret_cast<ushort4*>(&x_lo[t][i4 * 4]) = lo;
    }
    __syncthreads();

    // ---- layer 1: h = relu(x @ W1 + b1); wave w -> h cols [w*64, w*64+64) ----
    bf16x8 xa_h[2][2], xa_l[2][2];     // [row-tile][k-step]
    #pragma unroll
    for (int rt = 0; rt < 2; ++rt)
        #pragma unroll
        for (int kk = 0; kk < 2; ++kk) {
            xa_h[rt][kk] = *reinterpret_cast<const bf16x8*>(&x_hi[rt * 16 + lr][kk * 32 + lg * 8]);
            xa_l[rt][kk] = *reinterpret_cast<const bf16x8*>(&x_lo[rt * 16 + lr][kk * 32 + lg * 8]);
        }

    #pragma unroll
    for (int j = 0; j < 4; ++j) {
        const int n = w * 64 + j * 16 + lr;
        float bv = b1p[n];
        f32x4 a0 = {bv, bv, bv, bv};
        f32x4 a1 = {bv, bv, bv, bv};
        #pragma unroll
        for (int kk = 0; kk < 2; ++kk) {
            const float* wp = W1p + (size_t)(kk * 32 + lg * 8) * HH + n;
            bf16x8 bh, bl;
            #pragma unroll
            for (int i = 0; i < 8; ++i) {
                float wv = wp[(size_t)i * HH];
                unsigned short h_ = f2bf(wv);
                bh[i] = (short)h_;
                bl[i] = (short)f2bf_t(wv - bf2f(h_));
            }
            a0 = __builtin_amdgcn_mfma_f32_16x16x32_bf16(xa_h[0][kk], bh, a0, 0, 0, 0);
            a0 = __builtin_amdgcn_mfma_f32_16x16x32_bf16(xa_h[0][kk], bl, a0, 0, 0, 0);
            a0 = __builtin_amdgcn_mfma_f32_16x16x32_bf16(xa_l[0][kk], bh, a0, 0, 0, 0);
            a1 = __builtin_amdgcn_mfma_f32_16x16x32_bf16(xa_h[1][kk], bh, a1, 0, 0, 0);
            a1 = __builtin_amdgcn_mfma_f32_16x16x32_bf16(xa_h[1][kk], bl, a1, 0, 0, 0);
            a1 = __builtin_amdgcn_mfma_f32_16x16x32_bf16(xa_l[1][kk], bh, a1, 0, 0, 0);
        }
        #pragma unroll
        for (int r = 0; r < 4; ++r) {
            float h0 = fmaxf(a0[r], 0.0f);
            unsigned short hh0 = f2bf(h0);
            h_hi[lg * 4 + r][n] = hh0;
            h_lo[lg * 4 + r][n] = f2bf_t(h0 - bf2f(hh0));
            float h1 = fmaxf(a1[r], 0.0f);
            unsigned short hh1 = f2bf(h1);
            h_hi[16 + lg * 4 + r][n] = hh1;
            h_lo[16 + lg * 4 + r][n] = f2bf_t(h1 - bf2f(hh1));
        }
    }
    __syncthreads();

    // ---- layer 2: z = h @ W2 + b2 + te; direct global B-frags, 1-ahead prefetch ----
    float bias2[4];
    #pragma unroll
    for (int j = 0; j < 4; ++j) {
        int n = w * 64 + j * 16 + lr;
        bias2[j] = b2p[n] + tep[n];
    }
    f32x4 acc[2][4];
    #pragma unroll
    for (int rt = 0; rt < 2; ++rt)
        #pragma unroll
        for (int j = 0; j < 4; ++j) {
            f32x4 t0 = {bias2[j], bias2[j], bias2[j], bias2[j]};
            acc[rt][j] = t0;
        }

    // preload frag (kk=0, j=0)
    float cur[8];
    #pragma unroll
    for (int i = 0; i < 8; ++i)
        cur[i] = W2p[(size_t)(lg * 8 + i) * EE + (w * 64 + lr)];

    for (int kk = 0; kk < 16; ++kk) {
        bf16x8 ah0 = *reinterpret_cast<const bf16x8*>(&h_hi[lr][kk * 32 + lg * 8]);
        bf16x8 al0 = *reinterpret_cast<const bf16x8*>(&h_lo[lr][kk * 32 + lg * 8]);
        bf16x8 ah1 = *reinterpret_cast<const bf16x8*>(&h_hi[16 + lr][kk * 32 + lg * 8]);
        bf16x8 al1 = *reinterpret_cast<const bf16x8*>(&h_lo[16 + lr][kk * 32 + lg * 8]);
        #pragma unroll
        for (int j = 0; j < 4; ++j) {
            // issue next frag's loads first (overlap with convert+MFMA below)
            int nkk = (j == 3) ? kk + 1 : kk;
            int nj  = (j == 3) ? 0 : j + 1;
            float nxt[8];
            if (nkk < 16) {
                const float* wp = W2p + (size_t)(nkk * 32 + lg * 8) * EE + (w * 64 + nj * 16 + lr);
                #pragma unroll
                for (int i = 0; i < 8; ++i) nxt[i] = wp[(size_t)i * EE];
            } else {
                #pragma unroll
                for (int i = 0; i < 8; ++i) nxt[i] = 0.0f;
            }
            // convert current frag (hi RTNE, lo truncated)
            bf16x8 bh, bl;
            #pragma unroll
            for (int i = 0; i < 8; ++i) {
                unsigned short hb = f2bf(cur[i]);
                bh[i] = (short)hb;
                bl[i] = (short)f2bf_t(cur[i] - bf2f(hb));
            }
            acc[0][j] = __builtin_amdgcn_mfma_f32_16x16x32_bf16(ah0, bh, acc[0][j], 0, 0, 0);
            acc[0][j] = __builtin_amdgcn_mfma_f32_16x16x32_bf16(ah0, bl, acc[0][j], 0, 0, 0);
            acc[0][j] = __builtin_amdgcn_mfma_f32_16x16x32_bf16(al0, bh, acc[0][j], 0, 0, 0);
            acc[1][j] = __builtin_amdgcn_mfma_f32_16x16x32_bf16(ah1, bh, acc[1][j], 0, 0, 0);
            acc[1][j] = __builtin_amdgcn_mfma_f32_16x16x32_bf16(ah1, bl, acc[1][j], 0, 0, 0);
            acc[1][j] = __builtin_amdgcn_mfma_f32_16x16x32_bf16(al1, bh, acc[1][j], 0, 0, 0);
            #pragma unroll
            for (int i = 0; i < 8; ++i) cur[i] = nxt[i];
        }
    }

    // ---- epilogue: out[b, m*T + row, n] ----
    float* outp = out + ((size_t)(b * MM + m) * TT) * EE;
    #pragma unroll
    for (int rt = 0; rt < 2; ++rt)
        #pragma unroll
        for (int j = 0; j < 4; ++j) {
            int n = w * 64 + j * 16 + lr;
            #pragma unroll
            for (int r = 0; r < 4; ++r) {
                int row = rt * 16 + lg * 4 + r;
                outp[(size_t)row * EE + n] = acc[rt][j][r];
            }
        }
}

extern "C" void kernel_launch(void* const* d_in, const int* in_sizes, int n_in,
                              void* d_out, int out_size, void* d_ws, size_t ws_size,
                              hipStream_t stream) {
    const float* state   = (const float*)d_in[0];
    const int*   emb_ids = (const int*)d_in[1];
    const float* W1      = (const float*)d_in[2];
    const float* b1      = (const float*)d_in[3];
    const float* W2      = (const float*)d_in[4];
    const float* b2      = (const float*)d_in[5];
    const float* te      = (const float*)d_in[6];
    float*       out     = (float*)d_out;

    int* ent = (int*)d_ws;                    // 768 ints

    order_k<<<dim3(1), dim3(128), 0, stream>>>(emb_ids, ent);
    tok_mfma5<<<dim3(BB * MM), dim3(512), 0, stream>>>(
        state, ent, W1, b1, W2, b2, te, emb_ids, out);
}

// Round 12
// 374.113 us; speedup vs baseline: 2.7782x; 1.0345x over previous
//
#include <hip/hip_runtime.h>

// Problem constants (from reference)
#define MM   6
#define BB   128
#define TT   32
#define DIN  64
#define HH   512
#define EE   512
#define NEMB 32
#define XP   72    // padded x row (bf16): 144 B stride
#define HP   520   // padded h row (bf16): 1040 B stride
#define WS   514   // W2 tile row stride (u32): 2-way-free frag reads

typedef __attribute__((ext_vector_type(8))) short bf16x8;   // MFMA A/B frag
typedef __attribute__((ext_vector_type(4))) float f32x4;    // MFMA C/D frag

static __device__ __forceinline__ unsigned short f2bf(float f) {   // RTNE
    unsigned int u = __float_as_uint(f);
    u += 0x7FFFu + ((u >> 16) & 1u);
    return (unsigned short)(u >> 16);
}
static __device__ __forceinline__ float bf2f(unsigned short h) {
    return __uint_as_float(((unsigned int)h) << 16);
}
static __device__ __forceinline__ unsigned short f2bf_t(float f) { // truncate (lo parts)
    return (unsigned short)(__float_as_uint(f) >> 16);
}
static __device__ __forceinline__ unsigned int packsplit(float v) { // (lo<<16)|hi
    unsigned short hi = f2bf(v);
    unsigned short lo = f2bf_t(v - bf2f(hi));
    return (unsigned int)hi | ((unsigned int)lo << 16);
}

// ---- kernel 1: build id-major/m-secondary work order (1 block, 128 thr) ----
__global__ void order_k(const int* __restrict__ emb_ids, int* __restrict__ ent) {
    __shared__ int cnt_s[NEMB], psum_s[NEMB], slot_s[BB], id_s[BB];
    int t = threadIdx.x;
    if (t < NEMB) cnt_s[t] = 0;
    __syncthreads();
    if (t < BB) { int id = emb_ids[t]; id_s[t] = id; slot_s[t] = atomicAdd(&cnt_s[id], 1); }
    __syncthreads();
    if (t == 0) { int r = 0; for (int i = 0; i < NEMB; ++i) { psum_s[i] = r; r += cnt_s[i]; } }
    __syncthreads();
    if (t < BB) {
        int id = id_s[t], sl = slot_s[t], base = psum_s[id] * MM, c = cnt_s[id];
        for (int mm = 0; mm < MM; ++mm) ent[base + mm * c + sl] = (t << 3) | mm;
    }
}

// ---- kernel 2: per-(b,m) MLP; 1024 thr (16 waves x 32 out-cols);
//      layer2 W2 staged per 32-row k-slab into LDS (packed bf16 hi/lo) ----
// Fragment layouts (HW-verified, learn_hip m89/m92):
//   A (16x32): lane l, elem i -> A[l&15][(l>>4)*8 + i]
//   B (32x16): lane l, elem i -> B[(l>>4)*8 + i][l&15]
//   D (16x16): lane l, reg  r -> D[(l>>4)*4 + r][l&15]
// 3-term split: x*w ~= xh*wh + xh*wl + xl*wh (same MFMA order as R10 -> bit-identical)
__global__ __launch_bounds__(1024, 4) void tok_mfma6(
    const float* __restrict__ state,   // (B, T, M*DIN)
    const int*   __restrict__ ent,     // (768) sorted work items
    const float* __restrict__ W1,      // (M, NEMB, DIN, H)
    const float* __restrict__ b1,      // (M, NEMB, H)
    const float* __restrict__ W2,      // (M, NEMB, H, E)
    const float* __restrict__ b2,      // (M, NEMB, E)
    const float* __restrict__ te,      // (M, E)
    const int*   __restrict__ emb_ids, // (B)
    float* __restrict__ out)           // (B, M*T, E)
{
    __shared__ __align__(16) unsigned short x_hi[TT][XP];
    __shared__ __align__(16) unsigned short x_lo[TT][XP];
    __shared__ __align__(16) unsigned short h_hi[TT][HP];
    __shared__ __align__(16) unsigned short h_lo[TT][HP];
    __shared__ __align__(16) unsigned int  w2t[32 * WS];   // packed (lo<<16)|hi

    const int bid = blockIdx.x;
    const int s0  = (bid & 7) * 96 + (bid >> 3);   // XCD-chunked sorted index
    const int e   = ent[s0];
    const int b   = e >> 3;
    const int m   = e & 7;
    const int id  = emb_ids[b];

    const int tid  = threadIdx.x;
    const int lane = tid & 63;
    const int w    = tid >> 6;         // wave 0..15: owns out-cols [w*32, w*32+32)
    const int lr   = lane & 15;
    const int lg   = lane >> 4;

    const float* W1p = W1 + (size_t)(m * NEMB + id) * DIN * HH;
    const float* b1p = b1 + (size_t)(m * NEMB + id) * HH;
    const float* W2p = W2 + (size_t)(m * NEMB + id) * HH * EE;
    const float* b2p = b2 + (size_t)(m * NEMB + id) * EE;
    const float* tep = te + m * EE;
    const float* xg  = state + (size_t)b * TT * (MM * DIN) + m * DIN;

    // ---- issue slab-0 W2 loads EARLY (land during x-stage + layer1) ----
    const int srow = tid >> 7;            // 0..7
    const int scol = (tid & 127) * 4;     // 0..508
    const float* wsrc = W2p + (size_t)srow * EE + scol;
    float4 pa0 = *reinterpret_cast<const float4*>(wsrc);
    float4 pa1 = *reinterpret_cast<const float4*>(wsrc + (size_t)8 * EE);
    float4 pa2 = *reinterpret_cast<const float4*>(wsrc + (size_t)16 * EE);
    float4 pa3 = *reinterpret_cast<const float4*>(wsrc + (size_t)24 * EE);

    // ---- stage x (32x64 fp32) as bf16 hi/lo: 512 float4 slots ----
    if (tid < 512) {
        int t  = tid >> 4;
        int i4 = tid & 15;
        float4 v = *reinterpret_cast<const float4*>(xg + (size_t)t * (MM * DIN) + i4 * 4);
        ushort4 hi, lo;
        hi.x = f2bf(v.x); lo.x = f2bf_t(v.x - bf2f(hi.x));
        hi.y = f2bf(v.y); lo.y = f2bf_t(v.y - bf2f(hi.y));
        hi.z = f2bf(v.z); lo.z = f2bf_t(v.z - bf2f(hi.z));
        hi.w = f2bf(v.w); lo.w = f2bf_t(v.w - bf2f(hi.w));
        *reinterpret_cast<ushort4*>(&x_hi[t][i4 * 4]) = hi;
        *reinterpret_cast<ushort4*>(&x_lo[t][i4 * 4]) = lo;
    }
    __syncthreads();

    // ---- layer 1: h = relu(x @ W1 + b1); wave w -> h cols [w*32, w*32+32) ----
    bf16x8 xa_h[2][2], xa_l[2][2];     // [row-tile][k-step]
    #pragma unroll
    for (int rt = 0; rt < 2; ++rt)
        #pragma unroll
        for (int kk = 0; kk < 2; ++kk) {
            xa_h[rt][kk] = *reinterpret_cast<const bf16x8*>(&x_hi[rt * 16 + lr][kk * 32 + lg * 8]);
            xa_l[rt][kk] = *reinterpret_cast<const bf16x8*>(&x_lo[rt * 16 + lr][kk * 32 + lg * 8]);
        }

    #pragma unroll
    for (int j2 = 0; j2 < 2; ++j2) {
        const int n = w * 32 + j2 * 16 + lr;
        float bv = b1p[n];
        f32x4 a0 = {bv, bv, bv, bv};
        f32x4 a1 = {bv, bv, bv, bv};
        #pragma unroll
        for (int kk = 0; kk < 2; ++kk) {
            const float* wp = W1p + (size_t)(kk * 32 + lg * 8) * HH + n;
            bf16x8 bh, bl;
            #pragma unroll
            for (int i = 0; i < 8; ++i) {
                float wv = wp[(size_t)i * HH];
                unsigned short h_ = f2bf(wv);
                bh[i] = (short)h_;
                bl[i] = (short)f2bf_t(wv - bf2f(h_));
            }
            a0 = __builtin_amdgcn_mfma_f32_16x16x32_bf16(xa_h[0][kk], bh, a0, 0, 0, 0);
            a0 = __builtin_amdgcn_mfma_f32_16x16x32_bf16(xa_h[0][kk], bl, a0, 0, 0, 0);
            a0 = __builtin_amdgcn_mfma_f32_16x16x32_bf16(xa_l[0][kk], bh, a0, 0, 0, 0);
            a1 = __builtin_amdgcn_mfma_f32_16x16x32_bf16(xa_h[1][kk], bh, a1, 0, 0, 0);
            a1 = __builtin_amdgcn_mfma_f32_16x16x32_bf16(xa_h[1][kk], bl, a1, 0, 0, 0);
            a1 = __builtin_amdgcn_mfma_f32_16x16x32_bf16(xa_l[1][kk], bh, a1, 0, 0, 0);
        }
        #pragma unroll
        for (int r = 0; r < 4; ++r) {
            float h0 = fmaxf(a0[r], 0.0f);
            unsigned short hh0 = f2bf(h0);
            h_hi[lg * 4 + r][n] = hh0;
            h_lo[lg * 4 + r][n] = f2bf_t(h0 - bf2f(hh0));
            float h1 = fmaxf(a1[r], 0.0f);
            unsigned short hh1 = f2bf(h1);
            h_hi[16 + lg * 4 + r][n] = hh1;
            h_lo[16 + lg * 4 + r][n] = f2bf_t(h1 - bf2f(hh1));
        }
    }

    // ---- layer 2 accumulators ----
    float bias2[2];
    #pragma unroll
    for (int j2 = 0; j2 < 2; ++j2) {
        int n = w * 32 + j2 * 16 + lr;
        bias2[j2] = b2p[n] + tep[n];
    }
    f32x4 acc[2][2];                    // [row-tile][j2]
    #pragma unroll
    for (int rt = 0; rt < 2; ++rt)
        #pragma unroll
        for (int j2 = 0; j2 < 2; ++j2) {
            f32x4 t0 = {bias2[j2], bias2[j2], bias2[j2], bias2[j2]};
            acc[rt][j2] = t0;
        }
    __syncthreads();   // h visible to all waves

    // ---- slab loop: 16 slabs x 32 k-rows ----
    for (int s = 0; s < 16; ++s) {
        // publish slab s (converted) to LDS tile; compiler waits vmcnt for pa*
        {
            unsigned int* wr0 = &w2t[(0 * 8 + srow) * WS + scol];
            wr0[0] = packsplit(pa0.x); wr0[1] = packsplit(pa0.y);
            wr0[2] = packsplit(pa0.z); wr0[3] = packsplit(pa0.w);
            unsigned int* wr1 = &w2t[(1 * 8 + srow) * WS + scol];
            wr1[0] = packsplit(pa1.x); wr1[1] = packsplit(pa1.y);
            wr1[2] = packsplit(pa1.z); wr1[3] = packsplit(pa1.w);
            unsigned int* wr2 = &w2t[(2 * 8 + srow) * WS + scol];
            wr2[0] = packsplit(pa2.x); wr2[1] = packsplit(pa2.y);
            wr2[2] = packsplit(pa2.z); wr2[3] = packsplit(pa2.w);
            unsigned int* wr3 = &w2t[(3 * 8 + srow) * WS + scol];
            wr3[0] = packsplit(pa3.x); wr3[1] = packsplit(pa3.y);
            wr3[2] = packsplit(pa3.z); wr3[3] = packsplit(pa3.w);
        }
        __syncthreads();   // tile s visible

        // issue slab s+1 global loads (land during compute below)
        if (s < 15) {
            const float* nsrc = W2p + (size_t)((s + 1) * 32 + srow) * EE + scol;
            pa0 = *reinterpret_cast<const float4*>(nsrc);
            pa1 = *reinterpret_cast<const float4*>(nsrc + (size_t)8 * EE);
            pa2 = *reinterpret_cast<const float4*>(nsrc + (size_t)16 * EE);
            pa3 = *reinterpret_cast<const float4*>(nsrc + (size_t)24 * EE);
        }

        // A-frags (h) for k-step s
        bf16x8 ah0 = *reinterpret_cast<const bf16x8*>(&h_hi[lr][s * 32 + lg * 8]);
        bf16x8 al0 = *reinterpret_cast<const bf16x8*>(&h_lo[lr][s * 32 + lg * 8]);
        bf16x8 ah1 = *reinterpret_cast<const bf16x8*>(&h_hi[16 + lr][s * 32 + lg * 8]);
        bf16x8 al1 = *reinterpret_cast<const bf16x8*>(&h_lo[16 + lr][s * 32 + lg * 8]);

        #pragma unroll
        for (int j2 = 0; j2 < 2; ++j2) {
            const int n = w * 32 + j2 * 16 + lr;
            bf16x8 bh, bl;
            #pragma unroll
            for (int i = 0; i < 8; ++i) {
                unsigned int u = w2t[(lg * 8 + i) * WS + n];   // 2-way = free
                bh[i] = (short)(u & 0xFFFFu);
                bl[i] = (short)(u >> 16);
            }
            acc[0][j2] = __builtin_amdgcn_mfma_f32_16x16x32_bf16(ah0, bh, acc[0][j2], 0, 0, 0);
            acc[0][j2] = __builtin_amdgcn_mfma_f32_16x16x32_bf16(ah0, bl, acc[0][j2], 0, 0, 0);
            acc[0][j2] = __builtin_amdgcn_mfma_f32_16x16x32_bf16(al0, bh, acc[0][j2], 0, 0, 0);
            acc[1][j2] = __builtin_amdgcn_mfma_f32_16x16x32_bf16(ah1, bh, acc[1][j2], 0, 0, 0);
            acc[1][j2] = __builtin_amdgcn_mfma_f32_16x16x32_bf16(ah1, bl, acc[1][j2], 0, 0, 0);
            acc[1][j2] = __builtin_amdgcn_mfma_f32_16x16x32_bf16(al1, bh, acc[1][j2], 0, 0, 0);
        }
        __syncthreads();   // all waves done with tile s -> safe to overwrite
    }

    // ---- epilogue: out[b, m*T + row, n] ----
    float* outp = out + ((size_t)(b * MM + m) * TT) * EE;
    #pragma unroll
    for (int rt = 0; rt < 2; ++rt)
        #pragma unroll
        for (int j2 = 0; j2 < 2; ++j2) {
            int n = w * 32 + j2 * 16 + lr;
            #pragma unroll
            for (int r = 0; r < 4; ++r) {
                int row = rt * 16 + lg * 4 + r;
                outp[(size_t)row * EE + n] = acc[rt][j2][r];
            }
        }
}

extern "C" void kernel_launch(void* const* d_in, const int* in_sizes, int n_in,
                              void* d_out, int out_size, void* d_ws, size_t ws_size,
                              hipStream_t stream) {
    const float* state   = (const float*)d_in[0];
    const int*   emb_ids = (const int*)d_in[1];
    const float* W1      = (const float*)d_in[2];
    const float* b1      = (const float*)d_in[3];
    const float* W2      = (const float*)d_in[4];
    const float* b2      = (const float*)d_in[5];
    const float* te      = (const float*)d_in[6];
    float*       out     = (float*)d_out;

    int* ent = (int*)d_ws;                    // 768 ints

    order_k<<<dim3(1), dim3(128), 0, stream>>>(emb_ids, ent);
    tok_mfma6<<<dim3(BB * MM), dim3(1024), 0, stream>>>(
        state, ent, W1, b1, W2, b2, te, emb_ids, out);
}